// Round 1
// 353.993 us; speedup vs baseline: 1.0002x; 1.0002x over previous
//
#include <hip/hip_runtime.h>
#include <math.h>

// IRREPS = [(0,8),(1,8),(2,8),(3,8),(4,8)]  TOTAL_DIM=200  BATCH=2048  CHANNELS=128
// input (2048,200,128) f32; sincos_* (2048,5,2) f32, [b,m,0]=sin(m*t), [b,m,1]=cos(m*t)
// out per irrep l: R_l(b) = Zalpha * A_l * Zbeta * A_l^T * Zgamma along the (2l+1) axis.
//
// R4 (this round): prologue de-serialization.
//  - sincos (30 floats) staged into LDS up front (coalesced, one load/thread)
//    -> M/R steps no longer chase dependent GLOBAL loads inside dynamic loops.
//  - M-step templated on L -> compile-time trip counts, all LDS reads hoisted.
//  - l=2 rows (5) prefetched into registers alongside l=0/l=1 before the first
//    barrier -> 9 KB/wave of HBM traffic in flight across the prologue barriers.

#define NBATCH 2048

// ---------- shared host/device helpers ----------
__host__ __device__ __forceinline__ double small_d_elem_hd(int L, int jp, int jm) {
  int mp = jp - L, m = jm - L;
  double f[10];
  f[0] = 1.0;
  for (int i = 1; i < 10; ++i) f[i] = f[i - 1] * (double)i;
  double pref = sqrt(f[L + mp] * f[L - mp] * f[L + m] * f[L - m]);
  const double c  =  0.70710678118654752440;   // cos(-pi/4)
  const double sn = -0.70710678118654752440;   // sin(-pi/4)
  double tot = 0.0;
  int s0 = (m - mp) > 0 ? (m - mp) : 0;
  int s1 = (L + m) < (L - mp) ? (L + m) : (L - mp);
  for (int s = s0; s <= s1; ++s) {
    double den  = f[L + m - s] * f[s] * f[mp - m + s] * f[L - mp - s];
    double term = (((mp - m + s) & 1) ? -1.0 : 1.0) / den;
    int e1 = 2 * L + m - mp - 2 * s;
    int e2 = mp - m + 2 * s;
    double p1 = 1.0, p2 = 1.0;
    for (int t = 0; t < e1; ++t) p1 *= c;
    for (int t = 0; t < e2; ++t) p2 *= sn;
    tot += term * p1 * p2;
  }
  return pref * tot;
}

__host__ __device__ __forceinline__ int urow_entries_hd(int L, int p, int* c, double* r, int* ph) {
  const double s2 = 0.70710678118654752440;  // 1/sqrt(2)
  int m = p - L;
  if (m == 0) { c[0] = L; r[0] = 1.0; ph[0] = 0; return 1; }
  if (m > 0) {
    c[0] = L + m; r[0] = ((m & 1) ? -s2 : s2); ph[0] = 0;
    c[1] = L - m; r[1] = s2;                   ph[1] = 0;
    return 2;
  }
  int mu = -m;
  c[0] = L - mu; r[0] = s2;                    ph[0] = 1;
  c[1] = L + mu; r[1] = ((mu & 1) ? s2 : -s2); ph[1] = 1;
  return 2;
}

// ---------- host: build all A_l, concatenated {1,9,25,49,81} = 165 floats ----------
struct APack { float a[165]; };

static void host_compute_A(APack* out) {
  const int offs[5] = {0, 1, 10, 35, 84};
  for (int L = 0; L <= 4; ++L) {
    const int D = 2 * L + 1;
    double dsm[81];
    for (int jp = 0; jp < D; ++jp)
      for (int jm = 0; jm < D; ++jm)
        dsm[jp * D + jm] = small_d_elem_hd(L, jp, jm);
    for (int p = 0; p < D; ++p)
      for (int q = 0; q < D; ++q) {
        int c1[2], ph1[2], c2[2], ph2[2];
        double r1[2], r2[2];
        int n1 = urow_entries_hd(L, p, c1, r1, ph1);
        int n2 = urow_entries_hd(L, q, c2, r2, ph2);
        double acc = 0.0;
        for (int a = 0; a < n1; ++a)
          for (int bq = 0; bq < n2; ++bq) {
            int tp = ((c1[a] - c2[bq]) + ph1[a] - ph2[bq] + 12) & 3;  // power of i mod 4
            double v = r1[a] * r2[bq] * dsm[c1[a] * D + c2[bq]];
            if (tp == 0) acc += v;
            else if (tp == 2) acc -= v;
          }
        out->a[offs[L] + p * D + q] = (float)acc;
      }
  }
}

// ---------- streaming apply for one irrep (rows RB + g*D .. ), R at Rsm+RO ----------
template <int L, int RB, int RO>
__device__ __forceinline__ void apply_block(const float4* __restrict__ ib,
                                            float4* __restrict__ ob,
                                            const float* __restrict__ Rsm, int g) {
  constexpr int D = 2 * L + 1;
  const float4* ip = ib + (RB + g * D) * 32;
  float4* op = ob + (RB + g * D) * 32;
  const float* R = Rsm + RO;
  float4 x[D];
#pragma unroll
  for (int j = 0; j < D; ++j) x[j] = ip[j * 32];
#pragma unroll
  for (int i = 0; i < D; ++i) {
    float r = R[i * D];
    float4 a;
    a.x = r * x[0].x; a.y = r * x[0].y; a.z = r * x[0].z; a.w = r * x[0].w;
#pragma unroll
    for (int j = 1; j < D; ++j) {
      r = R[i * D + j];
      a.x = fmaf(r, x[j].x, a.x);
      a.y = fmaf(r, x[j].y, a.y);
      a.z = fmaf(r, x[j].z, a.z);
      a.w = fmaf(r, x[j].w, a.w);
    }
    op[i * 32] = a;
  }
}

// ---------- M-step, templated on L: compile-time trip counts, LDS-only reads ----------
template <int Lc>
__device__ __forceinline__ float mstep(const float* __restrict__ Asm,
                                       const float* __restrict__ SC,
                                       int i, int j) {
  constexpr int D = 2 * Lc + 1;
  constexpr int OFF = (Lc == 0) ? 0 : (Lc == 1) ? 1 : (Lc == 2) ? 10 : (Lc == 3) ? 35 : 84;
  float acc = 0.0f;
#pragma unroll
  for (int ii = 0; ii < D; ++ii) {
    const int mm = ii - Lc;
    const int am = mm < 0 ? -mm : mm;
    const float sgn = (float)((mm > 0) - (mm < 0));
    const float cb = SC[10 + am * 2 + 1];
    const float sv = sgn * SC[10 + am * 2 + 0];
    acc += Asm[OFF + i * D + ii] *
           (cb * Asm[OFF + j * D + ii] + sv * Asm[OFF + j * D + (2 * Lc - ii)]);
  }
  return acc;
}

__global__ __launch_bounds__(256, 4) void wigner_fused3(
    APack Ap,  // MUST be first arg: read via kernarg segment at offset 0
    const float* __restrict__ in, const float* __restrict__ sa,
    const float* __restrict__ sb, const float* __restrict__ sg,
    float* __restrict__ out) {
  (void)Ap;
  __shared__ float Asm[165];
  __shared__ float Msm[165];
  __shared__ float Rsm[165];
  __shared__ float SCsm[30];  // [0..9]=sa, [10..19]=sb, [20..29]=sg for this batch

  const int t = threadIdx.x;
  const int b = blockIdx.x;
  const int g = t >> 5;   // mult 0..7
  const int q = t & 31;   // float4 channel-quad

  const float4* ib = (const float4*)in + (size_t)b * 6400 + q;  // 200 rows * 32 quads
  float4* ob = (float4*)out + (size_t)b * 6400 + q;

  // A from kernarg segment (offset 0) -> LDS; sincos -> LDS (issued first).
  const float* Ak = (const float*)__builtin_amdgcn_kernarg_segment_ptr();
  if (t < 165) Asm[t] = Ak[t];
  if (t < 10)       SCsm[t] = sa[b * 10 + t];
  else if (t < 20)  SCsm[t] = sb[b * 10 + (t - 10)];
  else if (t < 30)  SCsm[t] = sg[b * 10 + (t - 20)];

  // Prefetch l=0 (row g), l=1 (rows 8+g*3+j), l=2 (rows 32+g*5+j): 9 rows = 9KB/wave
  // of HBM traffic in flight across the prologue barriers.
  float4 p0 = ib[g * 32];
  float4 p1[3];
#pragma unroll
  for (int j = 0; j < 3; ++j) p1[j] = ib[(8 + g * 3 + j) * 32];
  float4 p2[5];
#pragma unroll
  for (int j = 0; j < 5; ++j) p2[j] = ib[(32 + g * 5 + j) * 32];

  // thread -> (L, off, i, j) in concatenated 165 layout
  int L = 0, off = 0;
  if (t >= 84) { L = 4; off = 84; }
  else if (t >= 35) { L = 3; off = 35; }
  else if (t >= 10) { L = 2; off = 10; }
  else if (t >= 1)  { L = 1; off = 1; }
  const int D = 2 * L + 1;
  const int loc = t - off;
  const int i = loc / D;
  const int j = loc - i * D;
  __syncthreads();

  // M[i][j] = sum_ii A[i][ii] * (cb_ii * A[j][ii] + sbv_ii * A[j][2L-ii])  (LDS-only)
  if (t < 165) {
    float acc;
    if      (L == 0) acc = mstep<0>(Asm, SCsm, i, j);
    else if (L == 1) acc = mstep<1>(Asm, SCsm, i, j);
    else if (L == 2) acc = mstep<2>(Asm, SCsm, i, j);
    else if (L == 3) acc = mstep<3>(Asm, SCsm, i, j);
    else             acc = mstep<4>(Asm, SCsm, i, j);
    Msm[t] = acc;
  }
  __syncthreads();

  // R[p][k] = ca_p*(cg_k*M[p][k] - sgv_k*M[p][2L-k]) + sav_p*(cg_k*M[2L-p][k] - sgv_k*M[2L-p][2L-k])
  if (t < 165) {
    const int p = i, k = j;
    const int mmp = p - L, amp = mmp < 0 ? -mmp : mmp;
    const float sgp = (float)((mmp > 0) - (mmp < 0));
    const float cap = SCsm[amp * 2 + 1];
    const float sav = sgp * SCsm[amp * 2 + 0];
    const int mmk = k - L, amk = mmk < 0 ? -mmk : mmk;
    const float sgk = (float)((mmk > 0) - (mmk < 0));
    const float cgk = SCsm[20 + amk * 2 + 1];
    const float sgv = sgk * SCsm[20 + amk * 2 + 0];
    const float m00 = Msm[off + p * D + k];
    const float m01 = Msm[off + p * D + (2 * L - k)];
    const float m10 = Msm[off + (2 * L - p) * D + k];
    const float m11 = Msm[off + (2 * L - p) * D + (2 * L - k)];
    Rsm[t] = cap * (cgk * m00 - sgv * m01) + sav * (cgk * m10 - sgv * m11);
  }
  __syncthreads();

  // l=0 from prefetched register
  {
    float r0 = Rsm[0];
    float4 a;
    a.x = r0 * p0.x; a.y = r0 * p0.y; a.z = r0 * p0.z; a.w = r0 * p0.w;
    ob[g * 32] = a;
  }
  // l=1 (3x3) from prefetched registers, R at Rsm+1
  {
    const float* R1 = Rsm + 1;
#pragma unroll
    for (int i2 = 0; i2 < 3; ++i2) {
      float r = R1[i2 * 3];
      float4 a;
      a.x = r * p1[0].x; a.y = r * p1[0].y; a.z = r * p1[0].z; a.w = r * p1[0].w;
#pragma unroll
      for (int j2 = 1; j2 < 3; ++j2) {
        r = R1[i2 * 3 + j2];
        a.x = fmaf(r, p1[j2].x, a.x);
        a.y = fmaf(r, p1[j2].y, a.y);
        a.z = fmaf(r, p1[j2].z, a.z);
        a.w = fmaf(r, p1[j2].w, a.w);
      }
      ob[(8 + g * 3 + i2) * 32] = a;
    }
  }
  // l=2 (5x5) from prefetched registers, R at Rsm+10
  {
    const float* R2 = Rsm + 10;
#pragma unroll
    for (int i2 = 0; i2 < 5; ++i2) {
      float r = R2[i2 * 5];
      float4 a;
      a.x = r * p2[0].x; a.y = r * p2[0].y; a.z = r * p2[0].z; a.w = r * p2[0].w;
#pragma unroll
      for (int j2 = 1; j2 < 5; ++j2) {
        r = R2[i2 * 5 + j2];
        a.x = fmaf(r, p2[j2].x, a.x);
        a.y = fmaf(r, p2[j2].y, a.y);
        a.z = fmaf(r, p2[j2].z, a.z);
        a.w = fmaf(r, p2[j2].w, a.w);
      }
      ob[(32 + g * 5 + i2) * 32] = a;
    }
  }
  // l=3,4 streamed
  apply_block<3, 72,  35>(ib, ob, Rsm, g);
  apply_block<4, 128, 84>(ib, ob, Rsm, g);
}

extern "C" void kernel_launch(void* const* d_in, const int* in_sizes, int n_in,
                              void* d_out, int out_size, void* d_ws, size_t ws_size,
                              hipStream_t stream) {
  const float* in = (const float*)d_in[0];
  const float* sa = (const float*)d_in[1];
  const float* sb = (const float*)d_in[2];
  const float* sg = (const float*)d_in[3];
  float* out = (float*)d_out;

  APack Ap;
  host_compute_A(&Ap);

  wigner_fused3<<<dim3(NBATCH), 256, 0, stream>>>(Ap, in, sa, sb, sg, out);
}